// Round 14
// baseline (192.785 us; speedup 1.0000x reference)
//
#include <hip/hip_runtime.h>
#include <hip/hip_bf16.h>
#include <math.h>

// EmbeddingAlignerOT on MI355X.
// R12: GEMM1 rewritten as 256x256-tile 8-wave phase-pipelined kernel
// (T3+T4+T5): BK=64, 16 K-tiles x 4 phases; per phase {12 ds_read_b128
// (chunk-XOR swizzled: LDS[r][ch]=g[r][ch^(r&7)]) | stage 2 slabs of tile
// T+1 (per-wave slab assignment = own halves) | barrier | setprio+16 MFMA |
// [ph3: vmcnt(0)] | barrier}. LDS 128KB dbuf. GEMM2/3 + rest: R11 verbatim.
// Workspace (~103.2 MB): [0,32M) s_bf -> K+KT after gemm1 | [32M,34M) W_bf ->
// ua/ub/va/vb | [34M,66M) g_bf | [66M,98M) t_bf -> gTv | [98M..) scalars.

typedef __bf16 bf16_t;
typedef __bf16 bf16x8 __attribute__((ext_vector_type(8)));
typedef float  f32x4  __attribute__((ext_vector_type(4)));

#define NBATCH 32
#define NS 512
#define NG 512
#define NH 1024
#define M_REAL 2
#define N_TOT 100

__device__ __forceinline__ void async_copy16(const void* gsrc, void* ldst) {
  __builtin_amdgcn_global_load_lds(
      (__attribute__((address_space(1))) void*)gsrc,
      (__attribute__((address_space(3))) void*)ldst, 16, 0, 0);
}

// ---------- fp32 -> bf16 convert, src and W in one dispatch ----------
__global__ __launch_bounds__(256) void cvt2_kernel(const float* __restrict__ a,
                                                   bf16_t* __restrict__ outa, int n8a,
                                                   const float* __restrict__ b,
                                                   bf16_t* __restrict__ outb) {
  int i = blockIdx.x * 256 + threadIdx.x;
  const float* src;
  bf16_t* dst;
  int idx;
  if (i < n8a) { src = a; dst = outa; idx = i; }
  else         { src = b; dst = outb; idx = i - n8a; }
  const float4* p = (const float4*)src + (size_t)idx * 2;
  float4 x = p[0], y = p[1];
  bf16x8 o;
  o[0] = (__bf16)x.x; o[1] = (__bf16)x.y; o[2] = (__bf16)x.z; o[3] = (__bf16)x.w;
  o[4] = (__bf16)y.x; o[5] = (__bf16)y.y; o[6] = (__bf16)y.z; o[7] = (__bf16)y.w;
  ((bf16x8*)dst)[idx] = o;
}

// ---------- target: convert to bf16 + fp32 row norms ----------
__global__ __launch_bounds__(128) void prep_g_kernel(const float* __restrict__ g,
                                                     bf16_t* __restrict__ gb,
                                                     float* __restrict__ g2) {
  int row = blockIdx.x;   // B*G rows of length NH
  int t = threadIdx.x;    // 128
  const float* rp = g + (size_t)row * NH + t * 8;
  float4 a = *(const float4*)rp;
  float4 b = *(const float4*)(rp + 4);
  bf16x8 o;
  o[0] = (__bf16)a.x; o[1] = (__bf16)a.y; o[2] = (__bf16)a.z; o[3] = (__bf16)a.w;
  o[4] = (__bf16)b.x; o[5] = (__bf16)b.y; o[6] = (__bf16)b.z; o[7] = (__bf16)b.w;
  ((bf16x8*)(gb + (size_t)row * NH))[t] = o;
  float ss = a.x*a.x + a.y*a.y + a.z*a.z + a.w*a.w
           + b.x*b.x + b.y*b.y + b.z*b.z + b.w*b.w;
  #pragma unroll
  for (int ofs = 32; ofs > 0; ofs >>= 1) ss += __shfl_down(ss, ofs);
  __shared__ float wsum[2];
  if ((t & 63) == 0) wsum[t >> 6] = ss;
  __syncthreads();
  if (t == 0) g2[row] = wsum[0] + wsum[1];
}

// ---------- adjusted weights for BOTH sides in one dispatch ----------
__global__ __launch_bounds__(512) void weights2_kernel(
    const float* __restrict__ s2, const int* __restrict__ smask, float* __restrict__ swv,
    const float* __restrict__ g2, const int* __restrict__ gmask, float* __restrict__ gwv) {
  int which = blockIdx.x >> 5;
  int bb = blockIdx.x & 31, t = threadIdx.x;
  const float* n2 = which ? g2 : s2;
  const int* mask = which ? gmask : smask;
  float* wout = which ? gwv : swv;
  int idx = bb * 512 + t;
  float mag = sqrtf(n2[idx]) + 1e-12f;
  float w = (float)mask[idx] * mag + 1e-12f;
  float ss = w;
  #pragma unroll
  for (int ofs = 32; ofs > 0; ofs >>= 1) ss += __shfl_down(ss, ofs);
  __shared__ float red[8];
  __shared__ float tot;
  if ((t & 63) == 0) red[t >> 6] = ss;
  __syncthreads();
  if (t == 0) {
    float x = 0.f;
    #pragma unroll
    for (int i = 0; i < 8; i++) x += red[i];
    tot = fmaxf(x, 1e-12f);
  }
  __syncthreads();
  wout[idx] = w / tot;
}

// ---------- GEMM1: t = A @ W^T + bias, 256x256 tile, 8-wave phase pipeline ----
// M=16384, N=1024, K=1024. Grid 256 blocks (1/CU), 512 threads.
// LDS[buf][A/B][256*64] bf16, chunk-XOR swizzle LDS[r][ch]=g[r][ch^(r&7)].
// Per K-tile (BK=64): 4 phases (quadrants mq,nq); per phase 12 ds_read_b128,
// 2 staged slabs of tile T+1, barrier, 16 MFMA (setprio), barrier.
// vmcnt(0) once per tile at ph3 (loads issued ~4 phases earlier).
// Fused row-norm: sum (val+bias)^2 -> atomicAdd s2out (s2out pre-zeroed).
__global__ __launch_bounds__(512) void gemm1_8ph_kernel(
    const bf16_t* __restrict__ A, const bf16_t* __restrict__ Bm,
    bf16_t* __restrict__ outp, const float* __restrict__ bias,
    float* __restrict__ s2out) {
  constexpr int K = 1024;
  __shared__ bf16_t lds[2][2][256 * 64];   // 128 KB
  const int nwg = gridDim.x;               // 256
  const int lin = blockIdx.x;
  const int lin2 = (lin & 7) * (nwg >> 3) + (lin >> 3);  // XCD swizzle
  const int bx = lin2 & 3;                 // 1024/256 = 4 col tiles
  const int by = lin2 >> 2;                // 64 row tiles
  const int tid = threadIdx.x, lane = tid & 63, w = tid >> 6;  // 8 waves
  const int wr = w >> 2, wc = w & 3;       // 2 x 4 wave grid
  const int m0 = by * 256, n0 = bx * 256;  // n0 in [0,1024)
  // staging lane coords: slab = 8 rows x 64 cols; lane covers row sRow, chunk lane&7
  const int sRow = lane >> 3;
  const int sc8 = ((lane & 7) ^ sRow) * 8;   // pre-swizzled global chunk
  // fragment read coords
  const int rF = lane & 15;
  const int cx = lane & 7;                   // == rowF & 7
  const int ch0 = (((lane >> 4)) ^ cx) * 8;  // ksub=0 swizzled chunk (elems)
  const int ch1 = ch0 ^ 32;                  // ksub=1

  // stage 2 slabs (1 A + 1 B) of `tile` for phase j; per-wave assignment:
  // wave stages only rows within the A-half (wr) and B-half (wc>>1) it reads.
  auto stage2 = [&](int tile, int j) {
    const int buf = tile & 1;
    const int kt = tile << 6;
    int rA = wr * 128 + (4 * wc + j) * 8;
    async_copy16(A + (size_t)(m0 + rA + sRow) * K + kt + sc8,
                 &lds[buf][0][rA * 64]);
    int wB = wr * 2 + (wc & 1);
    int rB = (wc >> 1) * 128 + (4 * wB + j) * 8;
    async_copy16(Bm + (size_t)(n0 + rB + sRow) * K + kt + sc8,
                 &lds[buf][1][rB * 64]);
  };

  f32x4 acc[8][4];
  #pragma unroll
  for (int i = 0; i < 8; i++)
    #pragma unroll
    for (int j = 0; j < 4; j++) { f32x4 z = {0.f, 0.f, 0.f, 0.f}; acc[i][j] = z; }

  #pragma unroll
  for (int j = 0; j < 4; j++) stage2(0, j);
  asm volatile("s_waitcnt vmcnt(0)" ::: "memory");
  __builtin_amdgcn_s_barrier();

  for (int T = 0; T < 16; ++T) {
    const bf16_t* lA = &lds[T & 1][0][0];
    const bf16_t* lB = &lds[T & 1][1][0];
    #pragma unroll
    for (int ph = 0; ph < 4; ++ph) {
      const int mq = ph >> 1, nq = ph & 1;
      bf16x8 af[4][2], bf[2][2];
      #pragma unroll
      for (int mf = 0; mf < 4; mf++) {
        int row = (wr * 128 + mq * 64 + mf * 16 + rF) * 64;
        af[mf][0] = *(const bf16x8*)&lA[row + ch0];
        af[mf][1] = *(const bf16x8*)&lA[row + ch1];
      }
      #pragma unroll
      for (int nf = 0; nf < 2; nf++) {
        int row = (wc * 64 + nq * 32 + nf * 16 + rF) * 64;
        bf[nf][0] = *(const bf16x8*)&lB[row + ch0];
        bf[nf][1] = *(const bf16x8*)&lB[row + ch1];
      }
      if (T < 15) stage2(T + 1, ph);
      __builtin_amdgcn_s_barrier();
      __builtin_amdgcn_s_setprio(1);
      #pragma unroll
      for (int mf = 0; mf < 4; mf++)
        #pragma unroll
        for (int nf = 0; nf < 2; nf++) {
          acc[mq * 4 + mf][nq * 2 + nf] = __builtin_amdgcn_mfma_f32_16x16x32_bf16(
              af[mf][0], bf[nf][0], acc[mq * 4 + mf][nq * 2 + nf], 0, 0, 0);
          acc[mq * 4 + mf][nq * 2 + nf] = __builtin_amdgcn_mfma_f32_16x16x32_bf16(
              af[mf][1], bf[nf][1], acc[mq * 4 + mf][nq * 2 + nf], 0, 0, 0);
        }
      __builtin_amdgcn_s_setprio(0);
      if (ph == 3) {
        asm volatile("s_waitcnt vmcnt(0)" ::: "memory");
        __builtin_amdgcn_sched_barrier(0);
      }
      __builtin_amdgcn_s_barrier();
    }
  }

  // epilogue: C/D mapping col=lane&15, row=(lane>>4)*4+j
  const int r_off = (lane >> 4) * 4, c_off = lane & 15;
  float bs[4];
  #pragma unroll
  for (int ni = 0; ni < 4; ni++)
    bs[ni] = bias[n0 + wc * 64 + (ni >> 1) * 32 + (ni & 1) * 16 + c_off];
  float p[8][4];
  #pragma unroll
  for (int mi = 0; mi < 8; mi++)
    #pragma unroll
    for (int j = 0; j < 4; j++) p[mi][j] = 0.f;
  #pragma unroll
  for (int mi = 0; mi < 8; mi++) {
    int gm = m0 + wr * 128 + (mi >> 2) * 64 + (mi & 3) * 16 + r_off;
    #pragma unroll
    for (int ni = 0; ni < 4; ni++) {
      int gn = n0 + wc * 64 + (ni >> 1) * 32 + (ni & 1) * 16 + c_off;
      #pragma unroll
      for (int j = 0; j < 4; j++) {
        float tv = acc[mi][ni][j] + bs[ni];
        outp[(size_t)(gm + j) * 1024 + gn] = (__bf16)tv;
        p[mi][j] += tv * tv;
      }
    }
  }
  #pragma unroll
  for (int mi = 0; mi < 8; mi++) {
    int gm = m0 + wr * 128 + (mi >> 2) * 64 + (mi & 3) * 16 + r_off;
    #pragma unroll
    for (int j = 0; j < 4; j++) {
      float v = p[mi][j];
      v += __shfl_xor(v, 1);
      v += __shfl_xor(v, 2);
      v += __shfl_xor(v, 4);
      v += __shfl_xor(v, 8);
      if ((lane & 15) == 0) atomicAdd(&s2out[gm + j], v);
    }
  }
}

// ---------- C = A * B^T, 128x128 tile, BK=32, 4 waves (GEMM2/3) ----------
// Double-buffered K-loop, stage-at-top, counted vmcnt(4), raw barriers,
// chunk-XOR swizzle, XCD-aware bijective block swizzle.
// MODE 1: K = exp(-10*(sqrt(s2+g2-2C)*sw*gw+eps)) bf16 store (batched)
// MODE 2: out = u .* C, fp32 store (batched)
template <int MODE, int GX, int GY>
__global__ __launch_bounds__(256) void gemm_bt_kernel(
    const bf16_t* __restrict__ A, const bf16_t* __restrict__ Bm, int K_len,
    size_t strideAb, size_t strideBb,
    void* __restrict__ outp, size_t strideOb, int ldc,
    const float* __restrict__ s2, const float* __restrict__ g2,
    const float* __restrict__ sw, const float* __restrict__ gw,
    const float* __restrict__ uvec) {
  __shared__ bf16_t lds[2][2][128 * 32];   // [buf][A=0/B=1][row*32+col]
  const int nwg = gridDim.x;
  const int lin = blockIdx.x;
  const int lin2 = (lin & 7) * (nwg >> 3) + (lin >> 3);
  const int bx = lin2 % GX;
  const int by = (lin2 / GX) % GY;
  const int bz = lin2 / (GX * GY);
  const int tid = threadIdx.x, lane = tid & 63, wave = tid >> 6;
  const int wr = wave >> 1, wc = wave & 1;
  const bf16_t* Ab = A + (size_t)bz * strideAb;
  const bf16_t* Bb = Bm + (size_t)bz * strideBb;
  const int m0 = by * 128, n0 = bx * 128;
  const int rA = lane >> 2;
  const int c8s = (((lane & 3) ^ (rA & 3))) * 8;

  auto stage = [&](int kt, int buf) {
    #pragma unroll
    for (int c = 0; c < 2; c++) {
      int rg = (c * 4 + wave) * 16;
      async_copy16(Ab + (size_t)(m0 + rg + rA) * K_len + kt + c8s, &lds[buf][0][rg * 32]);
      async_copy16(Bb + (size_t)(n0 + rg + rA) * K_len + kt + c8s, &lds[buf][1][rg * 32]);
    }
  };

  f32x4 acc[4][4];
  #pragma unroll
  for (int i = 0; i < 4; i++)
    #pragma unroll
    for (int j = 0; j < 4; j++) { f32x4 z = {0.f, 0.f, 0.f, 0.f}; acc[i][j] = z; }

  const int chF = ((lane >> 4) ^ (lane & 3)) * 8;
  const int rF = lane & 15;

  stage(0, 0);
  int bufsel = 0;
  for (int kt = 0; kt < K_len; kt += 32) {
    if (kt + 32 < K_len) {
      stage(kt + 32, bufsel ^ 1);
      asm volatile("s_waitcnt vmcnt(4)" ::: "memory");
    } else {
      asm volatile("s_waitcnt vmcnt(0)" ::: "memory");
    }
    __builtin_amdgcn_s_barrier();
    bf16x8 af[4], bf[4];
    #pragma unroll
    for (int m = 0; m < 4; m++)
      af[m] = *(const bf16x8*)&lds[bufsel][0][(wr * 64 + m * 16 + rF) * 32 + chF];
    #pragma unroll
    for (int n = 0; n < 4; n++)
      bf[n] = *(const bf16x8*)&lds[bufsel][1][(wc * 64 + n * 16 + rF) * 32 + chF];
    #pragma unroll
    for (int m = 0; m < 4; m++)
      #pragma unroll
      for (int n = 0; n < 4; n++)
        acc[m][n] = __builtin_amdgcn_mfma_f32_16x16x32_bf16(af[m], bf[n], acc[m][n], 0, 0, 0);
    __builtin_amdgcn_s_barrier();
    bufsel ^= 1;
  }

  const int bo = bz * 512;
  const int row_base = m0 + wr * 64, col_base = n0 + wc * 64;
  const int r_off = (lane >> 4) * 4, c_off = lane & 15;
  #pragma unroll
  for (int m = 0; m < 4; m++) {
    #pragma unroll
    for (int n = 0; n < 4; n++) {
      #pragma unroll
      for (int j = 0; j < 4; j++) {
        int gm = row_base + m * 16 + r_off + j;
        int gn = col_base + n * 16 + c_off;
        float val = acc[m][n][j];
        if (MODE == 1) {
          float sq = s2[bo + gm] + g2[bo + gn] - 2.0f * val;
          float d = sqrtf(fmaxf(sq, 0.0f));
          float cost = d * sw[bo + gm] * gw[bo + gn] + 1e-12f;
          ((bf16_t*)outp + (size_t)bz * strideOb)[(size_t)gm * ldc + gn] =
              (__bf16)expf(-10.0f * cost);
        } else {
          ((float*)outp + (size_t)bz * strideOb)[(size_t)gm * ldc + gn] =
              uvec[bo + gm] * val;
        }
      }
    }
  }
}

// ---------- wide transpose: out[c][r] = in[r][c] * (SCALE ? v[r] : 1) ----------
template <int SCALE>
__global__ __launch_bounds__(256) void wide_transpose_kernel(
    const bf16_t* __restrict__ in, bf16_t* __restrict__ out,
    const float* __restrict__ vscale, int inRows, int inCols) {
  __shared__ bf16_t tl[32][66];
  size_t base = (size_t)blockIdx.z * inRows * inCols;
  int r0 = blockIdx.y * 32, c0 = blockIdx.x * 64;
  int row = threadIdx.x >> 3, cc8 = (threadIdx.x & 7) * 8;
  *(bf16x8*)&tl[row][cc8] =
      *(const bf16x8*)(in + base + (size_t)(r0 + row) * inCols + c0 + cc8);
  __syncthreads();
  int orow = threadIdx.x >> 2;
  int rq = (threadIdx.x & 3) * 8;
  bf16x8 o;
  if (SCALE) {
    const float* vp = vscale + (size_t)blockIdx.z * inRows + r0 + rq;
    float4 va = *(const float4*)vp;
    float4 vb = *(const float4*)(vp + 4);
    o[0] = (__bf16)((float)tl[rq + 0][orow] * va.x);
    o[1] = (__bf16)((float)tl[rq + 1][orow] * va.y);
    o[2] = (__bf16)((float)tl[rq + 2][orow] * va.z);
    o[3] = (__bf16)((float)tl[rq + 3][orow] * va.w);
    o[4] = (__bf16)((float)tl[rq + 4][orow] * vb.x);
    o[5] = (__bf16)((float)tl[rq + 5][orow] * vb.y);
    o[6] = (__bf16)((float)tl[rq + 6][orow] * vb.z);
    o[7] = (__bf16)((float)tl[rq + 7][orow] * vb.w);
  } else {
    #pragma unroll
    for (int i = 0; i < 8; i++) o[i] = tl[rq + i][orow];
  }
  *(bf16x8*)(out + base + (size_t)(c0 + orow) * inRows + r0 + rq) = o;
}

// ---------- Sinkhorn half-iteration, grid-wide ----------
template <int INIT>
__global__ __launch_bounds__(256) void sink_pass_kernel(
    const bf16_t* __restrict__ Mmat, const float* __restrict__ x,
    const float* __restrict__ w, float* __restrict__ y) {
  const int b = blockIdx.y;
  const int t = threadIdx.x;
  __shared__ float xs[512];
  if (!INIT) {
    ((float2*)xs)[t] = ((const float2*)(x + b * 512))[t];
    __syncthreads();
  }
  const int row = blockIdx.x * 64 + (t >> 2);
  const int seg = t & 3;
  const bf16_t* rp = Mmat + ((size_t)b * 512 + row) * 512;
  float sum = 0.f;
  #pragma unroll
  for (int j = 0; j < 16; j++) {
    bf16x8 kv = *(const bf16x8*)(rp + seg * 8 + j * 32);
    if (INIT) {
      sum += (float)kv[0] + (float)kv[1] + (float)kv[2] + (float)kv[3] +
             (float)kv[4] + (float)kv[5] + (float)kv[6] + (float)kv[7];
    } else {
      const float4* xp = (const float4*)&xs[seg * 8 + j * 32];
      float4 x0 = xp[0], x1 = xp[1];
      sum += (float)kv[0] * x0.x + (float)kv[1] * x0.y + (float)kv[2] * x0.z +
             (float)kv[3] * x0.w + (float)kv[4] * x1.x + (float)kv[5] * x1.y +
             (float)kv[6] * x1.z + (float)kv[7] * x1.w;
    }
  }
  if (INIT) sum *= (1.0f / 512.0f);
  sum += __shfl_xor(sum, 1);
  sum += __shfl_xor(sum, 2);
  if (seg == 0)
    y[b * 512 + row] = powf(w[b * 512 + row] / sum, 10.0f / 10.1f);
}

// ---------- Sinkhorn closed-form extrapolation to iteration 100 ----------
__global__ __launch_bounds__(512) void sink_final_kernel(
    const float* __restrict__ ua, const float* __restrict__ ub,
    const float* __restrict__ va, const float* __restrict__ vb,
    float* __restrict__ u_out, float* __restrict__ v_out, float Gf) {
  const int b = blockIdx.x, t = threadIdx.x, idx = b * 512 + t;
  const float ubv = ub[idx], vbv = vb[idx];
  float su = logf(ubv / ua[idx]);
  float sv = logf(vbv / va[idx]);
  #pragma unroll
  for (int ofs = 32; ofs > 0; ofs >>= 1) {
    su += __shfl_down(su, ofs);
    sv += __shfl_down(sv, ofs);
  }
  __shared__ float r0[8], r1[8];
  __shared__ float mu, mv;
  if ((t & 63) == 0) { r0[t >> 6] = su; r1[t >> 6] = sv; }
  __syncthreads();
  if (t == 0) {
    float a = 0.f, c = 0.f;
    #pragma unroll
    for (int i = 0; i < 8; i++) { a += r0[i]; c += r1[i]; }
    mu = a / 512.f; mv = c / 512.f;
  }
  __syncthreads();
  u_out[idx] = ubv * expf(Gf * mu);
  v_out[idx] = vbv * expf(Gf * mv);
}

extern "C" void kernel_launch(void* const* d_in, const int* in_sizes, int n_in,
                              void* d_out, int out_size, void* d_ws, size_t ws_size,
                              hipStream_t stream) {
  (void)in_sizes; (void)n_in; (void)out_size; (void)ws_size;
  const float* src = (const float*)d_in[0];   // [32,512,1024]
  const float* tgt = (const float*)d_in[1];   // [32,512,1024]
  const int* smask = (const int*)d_in[2];     // [32,512]
  const int* gmask = (const int*)d_in[3];     // [32,512]
  const float* W   = (const float*)d_in[4];   // [1024,1024]
  const float* bias = (const float*)d_in[5];  // [1024]
  float* out = (float*)d_out;                 // [32,512,1024]

  uint8_t* ws = (uint8_t*)d_ws;
  bf16_t* s_bf  = (bf16_t*)(ws + 0);          // 32 MB
  bf16_t* Kmat  = (bf16_t*)(ws + 0);          // reuse after gemm1: 16 MB
  bf16_t* KTmat = (bf16_t*)(ws + 16777216);   // 16 MB
  bf16_t* W_bf  = (bf16_t*)(ws + 33554432);   // 2 MB
  float* ua = (float*)(ws + 33554432);        // overwrite W_bf after gemm1
  float* ub = ua + 16384;
  float* va = ub + 16384;
  float* vb = va + 16384;
  bf16_t* g_bf  = (bf16_t*)(ws + 35651584);   // 32 MB
  bf16_t* t_bf  = (bf16_t*)(ws + 69206016);   // 32 MB
  bf16_t* gTv   = (bf16_t*)(ws + 69206016);   // reuse after gemm2
  float* s2  = (float*)(ws + 102760448);
  float* g2  = s2 + 16384;
  float* swv = g2 + 16384;
  float* gwv = swv + 16384;
  float* uv  = gwv + 16384;
  float* vv  = uv + 16384;

  // 1. conversions + g norms; zero s2 for fused-norm atomics
  cvt2_kernel<<<8704, 256, 0, stream>>>(src, s_bf, 2097152, W, W_bf);
  prep_g_kernel<<<16384, 128, 0, stream>>>(tgt, g_bf, g2);
  hipMemsetAsync(s2, 0, 16384 * sizeof(float), stream);

  // 2. t = s @ W^T + b  (M=16384,N=1024,K=1024) + fused row norms -> s2
  gemm1_8ph_kernel<<<256, 512, 0, stream>>>(s_bf, W_bf, t_bf, bias, s2);

  // 3. weights (both sides, one dispatch)
  weights2_kernel<<<64, 512, 0, stream>>>(s2, smask, swv, g2, gmask, gwv);

  // 4. K = exp(-10*cost)  (per batch 512x512, K=1024)
  gemm_bt_kernel<1, 4, 4><<<512, 256, 0, stream>>>(
      t_bf, g_bf, 1024, (size_t)512 * 1024, (size_t)512 * 1024,
      Kmat, (size_t)512 * 512, 512, s2, g2, swv, gwv, nullptr);

  // 5. K^T (wide transpose)
  wide_transpose_kernel<0><<<dim3(8, 16, 32), 256, 0, stream>>>(
      Kmat, KTmat, nullptr, NS, NG);

  // 6. Sinkhorn: 2 real iterations (4 passes) + extrapolation.
  dim3 pg(NS / 64, NBATCH);
  sink_pass_kernel<1><<<pg, 256, 0, stream>>>(Kmat, nullptr, swv, ua);   // u1
  sink_pass_kernel<0><<<pg, 256, 0, stream>>>(KTmat, ua, gwv, va);       // v1
  sink_pass_kernel<0><<<pg, 256, 0, stream>>>(Kmat, va, swv, ub);        // u2
  sink_pass_kernel<0><<<pg, 256, 0, stream>>>(KTmat, ub, gwv, vb);       // v2

  // G = sum_{j=1}^{100-M_REAL} fi^(2j) in double
  double fi2 = (10.0 / 10.1) * (10.0 / 10.1);
  double Gd = 0.0, pd = 1.0;
  for (int j = 0; j < (N_TOT - M_REAL); j++) { pd *= fi2; Gd += pd; }
  sink_final_kernel<<<32, 512, 0, stream>>>(ua, ub, va, vb, uv, vv, (float)Gd);

  // 7. gTv[h][g] = v[g]*g[g][h] (wide transpose + scale)
  wide_transpose_kernel<1><<<dim3(16, 16, 32), 256, 0, stream>>>(
      g_bf, gTv, vv, NG, NH);

  // 8. aligned = u .* (K @ gTv)  (per batch 512x1024, K=512)
  gemm_bt_kernel<2, 8, 4><<<1024, 256, 0, stream>>>(
      Kmat, gTv, 512, (size_t)512 * 512, (size_t)1024 * 512,
      out, (size_t)512 * 1024, 1024, nullptr, nullptr, nullptr, nullptr, uv);
}

// Round 15
// 188.785 us; speedup vs baseline: 1.0212x; 1.0212x over previous
//
#include <hip/hip_runtime.h>
#include <hip/hip_bf16.h>
#include <math.h>

// EmbeddingAlignerOT on MI355X.
// R15: fix R12's pipeline bug. GEMM1 (256x256, 8 waves, BK=64): stage ALL of
// tile T+1 at the TOP of tile T (8 loads), 4 MFMA phases with NO internal
// barriers (phases are per-wave independent), then ONE vmcnt(0) (loads have
// ~full-tile cover) + ONE barrier per tile (16 total vs R12's 128). R12's
// per-phase stagger drained a just-issued load every tile -> null.
// GEMM2/3 + rest: R11 verbatim.
// Workspace (~103.2 MB): [0,32M) s_bf -> K+KT after gemm1 | [32M,34M) W_bf ->
// ua/ub/va/vb | [34M,66M) g_bf | [66M,98M) t_bf -> gTv | [98M..) scalars.

typedef __bf16 bf16_t;
typedef __bf16 bf16x8 __attribute__((ext_vector_type(8)));
typedef float  f32x4  __attribute__((ext_vector_type(4)));

#define NBATCH 32
#define NS 512
#define NG 512
#define NH 1024
#define M_REAL 2
#define N_TOT 100

__device__ __forceinline__ void async_copy16(const void* gsrc, void* ldst) {
  __builtin_amdgcn_global_load_lds(
      (__attribute__((address_space(1))) void*)gsrc,
      (__attribute__((address_space(3))) void*)ldst, 16, 0, 0);
}

// ---------- fp32 -> bf16 convert, src and W in one dispatch ----------
__global__ __launch_bounds__(256) void cvt2_kernel(const float* __restrict__ a,
                                                   bf16_t* __restrict__ outa, int n8a,
                                                   const float* __restrict__ b,
                                                   bf16_t* __restrict__ outb) {
  int i = blockIdx.x * 256 + threadIdx.x;
  const float* src;
  bf16_t* dst;
  int idx;
  if (i < n8a) { src = a; dst = outa; idx = i; }
  else         { src = b; dst = outb; idx = i - n8a; }
  const float4* p = (const float4*)src + (size_t)idx * 2;
  float4 x = p[0], y = p[1];
  bf16x8 o;
  o[0] = (__bf16)x.x; o[1] = (__bf16)x.y; o[2] = (__bf16)x.z; o[3] = (__bf16)x.w;
  o[4] = (__bf16)y.x; o[5] = (__bf16)y.y; o[6] = (__bf16)y.z; o[7] = (__bf16)y.w;
  ((bf16x8*)dst)[idx] = o;
}

// ---------- target: convert to bf16 + fp32 row norms ----------
__global__ __launch_bounds__(128) void prep_g_kernel(const float* __restrict__ g,
                                                     bf16_t* __restrict__ gb,
                                                     float* __restrict__ g2) {
  int row = blockIdx.x;   // B*G rows of length NH
  int t = threadIdx.x;    // 128
  const float* rp = g + (size_t)row * NH + t * 8;
  float4 a = *(const float4*)rp;
  float4 b = *(const float4*)(rp + 4);
  bf16x8 o;
  o[0] = (__bf16)a.x; o[1] = (__bf16)a.y; o[2] = (__bf16)a.z; o[3] = (__bf16)a.w;
  o[4] = (__bf16)b.x; o[5] = (__bf16)b.y; o[6] = (__bf16)b.z; o[7] = (__bf16)b.w;
  ((bf16x8*)(gb + (size_t)row * NH))[t] = o;
  float ss = a.x*a.x + a.y*a.y + a.z*a.z + a.w*a.w
           + b.x*b.x + b.y*b.y + b.z*b.z + b.w*b.w;
  #pragma unroll
  for (int ofs = 32; ofs > 0; ofs >>= 1) ss += __shfl_down(ss, ofs);
  __shared__ float wsum[2];
  if ((t & 63) == 0) wsum[t >> 6] = ss;
  __syncthreads();
  if (t == 0) g2[row] = wsum[0] + wsum[1];
}

// ---------- adjusted weights for BOTH sides in one dispatch ----------
__global__ __launch_bounds__(512) void weights2_kernel(
    const float* __restrict__ s2, const int* __restrict__ smask, float* __restrict__ swv,
    const float* __restrict__ g2, const int* __restrict__ gmask, float* __restrict__ gwv) {
  int which = blockIdx.x >> 5;
  int bb = blockIdx.x & 31, t = threadIdx.x;
  const float* n2 = which ? g2 : s2;
  const int* mask = which ? gmask : smask;
  float* wout = which ? gwv : swv;
  int idx = bb * 512 + t;
  float mag = sqrtf(n2[idx]) + 1e-12f;
  float w = (float)mask[idx] * mag + 1e-12f;
  float ss = w;
  #pragma unroll
  for (int ofs = 32; ofs > 0; ofs >>= 1) ss += __shfl_down(ss, ofs);
  __shared__ float red[8];
  __shared__ float tot;
  if ((t & 63) == 0) red[t >> 6] = ss;
  __syncthreads();
  if (t == 0) {
    float x = 0.f;
    #pragma unroll
    for (int i = 0; i < 8; i++) x += red[i];
    tot = fmaxf(x, 1e-12f);
  }
  __syncthreads();
  wout[idx] = w / tot;
}

// ---------- GEMM1: t = A @ W^T + bias, 256x256 tile, 8-wave pipeline ----------
// M=16384, N=1024, K=1024. Grid 256 blocks (1/CU), 512 threads.
// LDS[buf][A/B][256*64] bf16, chunk-XOR swizzle LDS[r][ch]=g[r][ch^(r&7)].
// Per K-tile: stage_all(T+1) at top (8 loads/thread-wave), 4 phases of
// {12 ds_read_b128 + 16 MFMA}, then vmcnt(0)+barrier ONCE (T+1 loads had
// ~700cyc cover). Buf reuse safety: next stage_all targets buf[T&1], whose
// readers all passed this tile-end barrier.
// Fused row-norm: sum (val+bias)^2 -> atomicAdd s2out (s2out pre-zeroed).
__global__ __launch_bounds__(512) void gemm1_8ph_kernel(
    const bf16_t* __restrict__ A, const bf16_t* __restrict__ Bm,
    bf16_t* __restrict__ outp, const float* __restrict__ bias,
    float* __restrict__ s2out) {
  constexpr int K = 1024;
  __shared__ bf16_t lds[2][2][256 * 64];   // 128 KB
  const int nwg = gridDim.x;               // 256
  const int lin = blockIdx.x;
  const int lin2 = (lin & 7) * (nwg >> 3) + (lin >> 3);  // XCD swizzle
  const int bx = lin2 & 3;                 // 1024/256 = 4 col tiles
  const int by = lin2 >> 2;                // 64 row tiles
  const int tid = threadIdx.x, lane = tid & 63, w = tid >> 6;  // 8 waves
  const int wr = w >> 2, wc = w & 3;       // 2 x 4 wave grid
  const int m0 = by * 256, n0 = bx * 256;  // n0 in [0,1024)
  // staging lane coords: slab = 8 rows x 64 cols; lane covers row sRow, chunk lane&7
  const int sRow = lane >> 3;
  const int sc8 = ((lane & 7) ^ sRow) * 8;   // pre-swizzled global chunk
  // fragment read coords
  const int rF = lane & 15;
  const int cx = lane & 7;                   // == rowF & 7
  const int ch0 = (((lane >> 4)) ^ cx) * 8;  // ksub=0 swizzled chunk (elems)
  const int ch1 = ch0 ^ 32;                  // ksub=1

  // stage the ENTIRE A+B K-tile `tile` (8 loads: 4 A-slabs + 4 B-slabs,
  // per-wave slab assignment covering all 256 rows of each operand)
  auto stage_all = [&](int tile) {
    const int buf = tile & 1;
    const int kt = tile << 6;
    #pragma unroll
    for (int j = 0; j < 4; j++) {
      int rA = wr * 128 + (4 * wc + j) * 8;
      async_copy16(A + (size_t)(m0 + rA + sRow) * K + kt + sc8,
                   &lds[buf][0][rA * 64]);
      int wB = wr * 2 + (wc & 1);
      int rB = (wc >> 1) * 128 + (4 * wB + j) * 8;
      async_copy16(Bm + (size_t)(n0 + rB + sRow) * K + kt + sc8,
                   &lds[buf][1][rB * 64]);
    }
  };

  f32x4 acc[8][4];
  #pragma unroll
  for (int i = 0; i < 8; i++)
    #pragma unroll
    for (int j = 0; j < 4; j++) { f32x4 z = {0.f, 0.f, 0.f, 0.f}; acc[i][j] = z; }

  stage_all(0);
  asm volatile("s_waitcnt vmcnt(0)" ::: "memory");
  __builtin_amdgcn_s_barrier();

  for (int T = 0; T < 16; ++T) {
    if (T < 15) stage_all(T + 1);     // into buf[(T+1)&1]; its readers (tile
                                      // T-1) all passed the last barrier
    const bf16_t* lA = &lds[T & 1][0][0];
    const bf16_t* lB = &lds[T & 1][1][0];
    #pragma unroll
    for (int ph = 0; ph < 4; ++ph) {  // no barriers between phases
      const int mq = ph >> 1, nq = ph & 1;
      bf16x8 af[4][2], bf[2][2];
      #pragma unroll
      for (int mf = 0; mf < 4; mf++) {
        int row = (wr * 128 + mq * 64 + mf * 16 + rF) * 64;
        af[mf][0] = *(const bf16x8*)&lA[row + ch0];
        af[mf][1] = *(const bf16x8*)&lA[row + ch1];
      }
      #pragma unroll
      for (int nf = 0; nf < 2; nf++) {
        int row = (wc * 64 + nq * 32 + nf * 16 + rF) * 64;
        bf[nf][0] = *(const bf16x8*)&lB[row + ch0];
        bf[nf][1] = *(const bf16x8*)&lB[row + ch1];
      }
      __builtin_amdgcn_s_setprio(1);
      #pragma unroll
      for (int mf = 0; mf < 4; mf++)
        #pragma unroll
        for (int nf = 0; nf < 2; nf++) {
          acc[mq * 4 + mf][nq * 2 + nf] = __builtin_amdgcn_mfma_f32_16x16x32_bf16(
              af[mf][0], bf[nf][0], acc[mq * 4 + mf][nq * 2 + nf], 0, 0, 0);
          acc[mq * 4 + mf][nq * 2 + nf] = __builtin_amdgcn_mfma_f32_16x16x32_bf16(
              af[mf][1], bf[nf][1], acc[mq * 4 + mf][nq * 2 + nf], 0, 0, 0);
        }
      __builtin_amdgcn_s_setprio(0);
    }
    if (T < 15)
      asm volatile("s_waitcnt vmcnt(0)" ::: "memory");  // T+1 loads: ~full-tile cover
    __builtin_amdgcn_s_barrier();     // buf[T&1] reads done; T+1 data visible
  }

  // epilogue: C/D mapping col=lane&15, row=(lane>>4)*4+j
  const int r_off = (lane >> 4) * 4, c_off = lane & 15;
  float bs[4];
  #pragma unroll
  for (int ni = 0; ni < 4; ni++)
    bs[ni] = bias[n0 + wc * 64 + (ni >> 1) * 32 + (ni & 1) * 16 + c_off];
  float p[8][4];
  #pragma unroll
  for (int mi = 0; mi < 8; mi++)
    #pragma unroll
    for (int j = 0; j < 4; j++) p[mi][j] = 0.f;
  #pragma unroll
  for (int mi = 0; mi < 8; mi++) {
    int gm = m0 + wr * 128 + (mi >> 2) * 64 + (mi & 3) * 16 + r_off;
    #pragma unroll
    for (int ni = 0; ni < 4; ni++) {
      int gn = n0 + wc * 64 + (ni >> 1) * 32 + (ni & 1) * 16 + c_off;
      #pragma unroll
      for (int j = 0; j < 4; j++) {
        float tv = acc[mi][ni][j] + bs[ni];
        outp[(size_t)(gm + j) * 1024 + gn] = (__bf16)tv;
        p[mi][j] += tv * tv;
      }
    }
  }
  #pragma unroll
  for (int mi = 0; mi < 8; mi++) {
    int gm = m0 + wr * 128 + (mi >> 2) * 64 + (mi & 3) * 16 + r_off;
    #pragma unroll
    for (int j = 0; j < 4; j++) {
      float v = p[mi][j];
      v += __shfl_xor(v, 1);
      v += __shfl_xor(v, 2);
      v += __shfl_xor(v, 4);
      v += __shfl_xor(v, 8);
      if ((lane & 15) == 0) atomicAdd(&s2out[gm + j], v);
    }
  }
}

// ---------- C = A * B^T, 128x128 tile, BK=32, 4 waves (GEMM2/3) ----------
// Double-buffered K-loop, stage-at-top, counted vmcnt(4), raw barriers,
// chunk-XOR swizzle, XCD-aware bijective block swizzle.
// MODE 1: K = exp(-10*(sqrt(s2+g2-2C)*sw*gw+eps)) bf16 store (batched)
// MODE 2: out = u .* C, fp32 store (batched)
template <int MODE, int GX, int GY>
__global__ __launch_bounds__(256) void gemm_bt_kernel(
    const bf16_t* __restrict__ A, const bf16_t* __restrict__ Bm, int K_len,
    size_t strideAb, size_t strideBb,
    void* __restrict__ outp, size_t strideOb, int ldc,
    const float* __restrict__ s2, const float* __restrict__ g2,
    const float* __restrict__ sw, const float* __restrict__ gw,
    const float* __restrict__ uvec) {
  __shared__ bf16_t lds[2][2][128 * 32];   // [buf][A=0/B=1][row*32+col]
  const int nwg = gridDim.x;
  const int lin = blockIdx.x;
  const int lin2 = (lin & 7) * (nwg >> 3) + (lin >> 3);
  const int bx = lin2 % GX;
  const int by = (lin2 / GX) % GY;
  const int bz = lin2 / (GX * GY);
  const int tid = threadIdx.x, lane = tid & 63, wave = tid >> 6;
  const int wr = wave >> 1, wc = wave & 1;
  const bf16_t* Ab = A + (size_t)bz * strideAb;
  const bf16_t* Bb = Bm + (size_t)bz * strideBb;
  const int m0 = by * 128, n0 = bx * 128;
  const int rA = lane >> 2;
  const int c8s = (((lane & 3) ^ (rA & 3))) * 8;

  auto stage = [&](int kt, int buf) {
    #pragma unroll
    for (int c = 0; c < 2; c++) {
      int rg = (c * 4 + wave) * 16;
      async_copy16(Ab + (size_t)(m0 + rg + rA) * K_len + kt + c8s, &lds[buf][0][rg * 32]);
      async_copy16(Bb + (size_t)(n0 + rg + rA) * K_len + kt + c8s, &lds[buf][1][rg * 32]);
    }
  };

  f32x4 acc[4][4];
  #pragma unroll
  for (int i = 0; i < 4; i++)
    #pragma unroll
    for (int j = 0; j < 4; j++) { f32x4 z = {0.f, 0.f, 0.f, 0.f}; acc[i][j] = z; }

  const int chF = ((lane >> 4) ^ (lane & 3)) * 8;
  const int rF = lane & 15;

  stage(0, 0);
  int bufsel = 0;
  for (int kt = 0; kt < K_len; kt += 32) {
    if (kt + 32 < K_len) {
      stage(kt + 32, bufsel ^ 1);
      asm volatile("s_waitcnt vmcnt(4)" ::: "memory");
    } else {
      asm volatile("s_waitcnt vmcnt(0)" ::: "memory");
    }
    __builtin_amdgcn_s_barrier();
    bf16x8 af[4], bf[4];
    #pragma unroll
    for (int m = 0; m < 4; m++)
      af[m] = *(const bf16x8*)&lds[bufsel][0][(wr * 64 + m * 16 + rF) * 32 + chF];
    #pragma unroll
    for (int n = 0; n < 4; n++)
      bf[n] = *(const bf16x8*)&lds[bufsel][1][(wc * 64 + n * 16 + rF) * 32 + chF];
    #pragma unroll
    for (int m = 0; m < 4; m++)
      #pragma unroll
      for (int n = 0; n < 4; n++)
        acc[m][n] = __builtin_amdgcn_mfma_f32_16x16x32_bf16(af[m], bf[n], acc[m][n], 0, 0, 0);
    __builtin_amdgcn_s_barrier();
    bufsel ^= 1;
  }

  const int bo = bz * 512;
  const int row_base = m0 + wr * 64, col_base = n0 + wc * 64;
  const int r_off = (lane >> 4) * 4, c_off = lane & 15;
  #pragma unroll
  for (int m = 0; m < 4; m++) {
    #pragma unroll
    for (int n = 0; n < 4; n++) {
      #pragma unroll
      for (int j = 0; j < 4; j++) {
        int gm = row_base + m * 16 + r_off + j;
        int gn = col_base + n * 16 + c_off;
        float val = acc[m][n][j];
        if (MODE == 1) {
          float sq = s2[bo + gm] + g2[bo + gn] - 2.0f * val;
          float d = sqrtf(fmaxf(sq, 0.0f));
          float cost = d * sw[bo + gm] * gw[bo + gn] + 1e-12f;
          ((bf16_t*)outp + (size_t)bz * strideOb)[(size_t)gm * ldc + gn] =
              (__bf16)expf(-10.0f * cost);
        } else {
          ((float*)outp + (size_t)bz * strideOb)[(size_t)gm * ldc + gn] =
              uvec[bo + gm] * val;
        }
      }
    }
  }
}

// ---------- wide transpose: out[c][r] = in[r][c] * (SCALE ? v[r] : 1) ----------
template <int SCALE>
__global__ __launch_bounds__(256) void wide_transpose_kernel(
    const bf16_t* __restrict__ in, bf16_t* __restrict__ out,
    const float* __restrict__ vscale, int inRows, int inCols) {
  __shared__ bf16_t tl[32][66];
  size_t base = (size_t)blockIdx.z * inRows * inCols;
  int r0 = blockIdx.y * 32, c0 = blockIdx.x * 64;
  int row = threadIdx.x >> 3, cc8 = (threadIdx.x & 7) * 8;
  *(bf16x8*)&tl[row][cc8] =
      *(const bf16x8*)(in + base + (size_t)(r0 + row) * inCols + c0 + cc8);
  __syncthreads();
  int orow = threadIdx.x >> 2;
  int rq = (threadIdx.x & 3) * 8;
  bf16x8 o;
  if (SCALE) {
    const float* vp = vscale + (size_t)blockIdx.z * inRows + r0 + rq;
    float4 va = *(const float4*)vp;
    float4 vb = *(const float4*)(vp + 4);
    o[0] = (__bf16)((float)tl[rq + 0][orow] * va.x);
    o[1] = (__bf16)((float)tl[rq + 1][orow] * va.y);
    o[2] = (__bf16)((float)tl[rq + 2][orow] * va.z);
    o[3] = (__bf16)((float)tl[rq + 3][orow] * va.w);
    o[4] = (__bf16)((float)tl[rq + 4][orow] * vb.x);
    o[5] = (__bf16)((float)tl[rq + 5][orow] * vb.y);
    o[6] = (__bf16)((float)tl[rq + 6][orow] * vb.z);
    o[7] = (__bf16)((float)tl[rq + 7][orow] * vb.w);
  } else {
    #pragma unroll
    for (int i = 0; i < 8; i++) o[i] = tl[rq + i][orow];
  }
  *(bf16x8*)(out + base + (size_t)(c0 + orow) * inRows + r0 + rq) = o;
}

// ---------- Sinkhorn half-iteration, grid-wide ----------
template <int INIT>
__global__ __launch_bounds__(256) void sink_pass_kernel(
    const bf16_t* __restrict__ Mmat, const float* __restrict__ x,
    const float* __restrict__ w, float* __restrict__ y) {
  const int b = blockIdx.y;
  const int t = threadIdx.x;
  __shared__ float xs[512];
  if (!INIT) {
    ((float2*)xs)[t] = ((const float2*)(x + b * 512))[t];
    __syncthreads();
  }
  const int row = blockIdx.x * 64 + (t >> 2);
  const int seg = t & 3;
  const bf16_t* rp = Mmat + ((size_t)b * 512 + row) * 512;
  float sum = 0.f;
  #pragma unroll
  for (int j = 0; j < 16; j++) {
    bf16x8 kv = *(const bf16x8*)(rp + seg * 8 + j * 32);
    if (INIT) {
      sum += (float)kv[0] + (float)kv[1] + (float)kv[2] + (float)kv[3] +
             (float)kv[4] + (float)kv[5] + (float)kv[6] + (float)kv[7];
    } else {
      const float4* xp = (const float4*)&xs[seg * 8 + j * 32];
      float4 x0 = xp[0], x1 = xp[1];
      sum += (float)kv[0] * x0.x + (float)kv[1] * x0.y + (float)kv[2] * x0.z +
             (float)kv[3] * x0.w + (float)kv[4] * x1.x + (float)kv[5] * x1.y +
             (float)kv[6] * x1.z + (float)kv[7] * x1.w;
    }
  }
  if (INIT) sum *= (1.0f / 512.0f);
  sum += __shfl_xor(sum, 1);
  sum += __shfl_xor(sum, 2);
  if (seg == 0)
    y[b * 512 + row] = powf(w[b * 512 + row] / sum, 10.0f / 10.1f);
}

// ---------- Sinkhorn closed-form extrapolation to iteration 100 ----------
__global__ __launch_bounds__(512) void sink_final_kernel(
    const float* __restrict__ ua, const float* __restrict__ ub,
    const float* __restrict__ va, const float* __restrict__ vb,
    float* __restrict__ u_out, float* __restrict__ v_out, float Gf) {
  const int b = blockIdx.x, t = threadIdx.x, idx = b * 512 + t;
  const float ubv = ub[idx], vbv = vb[idx];
  float su = logf(ubv / ua[idx]);
  float sv = logf(vbv / va[idx]);
  #pragma unroll
  for (int ofs = 32; ofs > 0; ofs >>= 1) {
    su += __shfl_down(su, ofs);
    sv += __shfl_down(sv, ofs);
  }
  __shared__ float r0[8], r1[8];
  __shared__ float mu, mv;
  if ((t & 63) == 0) { r0[t >> 6] = su; r1[t >> 6] = sv; }
  __syncthreads();
  if (t == 0) {
    float a = 0.f, c = 0.f;
    #pragma unroll
    for (int i = 0; i < 8; i++) { a += r0[i]; c += r1[i]; }
    mu = a / 512.f; mv = c / 512.f;
  }
  __syncthreads();
  u_out[idx] = ubv * expf(Gf * mu);
  v_out[idx] = vbv * expf(Gf * mv);
}

extern "C" void kernel_launch(void* const* d_in, const int* in_sizes, int n_in,
                              void* d_out, int out_size, void* d_ws, size_t ws_size,
                              hipStream_t stream) {
  (void)in_sizes; (void)n_in; (void)out_size; (void)ws_size;
  const float* src = (const float*)d_in[0];   // [32,512,1024]
  const float* tgt = (const float*)d_in[1];   // [32,512,1024]
  const int* smask = (const int*)d_in[2];     // [32,512]
  const int* gmask = (const int*)d_in[3];     // [32,512]
  const float* W   = (const float*)d_in[4];   // [1024,1024]
  const float* bias = (const float*)d_in[5];  // [1024]
  float* out = (float*)d_out;                 // [32,512,1024]

  uint8_t* ws = (uint8_t*)d_ws;
  bf16_t* s_bf  = (bf16_t*)(ws + 0);          // 32 MB
  bf16_t* Kmat  = (bf16_t*)(ws + 0);          // reuse after gemm1: 16 MB
  bf16_t* KTmat = (bf16_t*)(ws + 16777216);   // 16 MB
  bf16_t* W_bf  = (bf16_t*)(ws + 33554432);   // 2 MB
  float* ua = (float*)(ws + 33554432);        // overwrite W_bf after gemm1
  float* ub = ua + 16384;
  float* va = ub + 16384;
  float* vb = va + 16384;
  bf16_t* g_bf  = (bf16_t*)(ws + 35651584);   // 32 MB
  bf16_t* t_bf  = (bf16_t*)(ws + 69206016);   // 32 MB
  bf16_t* gTv   = (bf16_t*)(ws + 69206016);   // reuse after gemm2
  float* s2  = (float*)(ws + 102760448);
  float* g2  = s2 + 16384;
  float* swv = g2 + 16384;
  float* gwv = swv + 16384;
  float* uv  = gwv + 16384;
  float* vv  = uv + 16384;

  // 1. conversions + g norms; zero s2 for fused-norm atomics
  cvt2_kernel<<<8704, 256, 0, stream>>>(src, s_bf, 2097152, W, W_bf);
  prep_g_kernel<<<16384, 128, 0, stream>>>(tgt, g_bf, g2);
  hipMemsetAsync(s2, 0, 16384 * sizeof(float), stream);

  // 2. t = s @ W^T + b  (M=16384,N=1024,K=1024) + fused row norms -> s2
  gemm1_8ph_kernel<<<256, 512, 0, stream>>>(s_bf, W_bf, t_bf, bias, s2);

  // 3. weights (both sides, one dispatch)
  weights2_kernel<<<64, 512, 0, stream>>>(s2, smask, swv, g2, gmask, gwv);

  // 4. K = exp(-10*cost)  (per batch 512x512, K=1024)
  gemm_bt_kernel<1, 4, 4><<<512, 256, 0, stream>>>(
      t_bf, g_bf, 1024, (size_t)512 * 1024, (size_t)512 * 1024,
      Kmat, (size_t)512 * 512, 512, s2, g2, swv, gwv, nullptr);

  // 5. K^T (wide transpose)
  wide_transpose_kernel<0><<<dim3(8, 16, 32), 256, 0, stream>>>(
      Kmat, KTmat, nullptr, NS, NG);

  // 6. Sinkhorn: 2 real iterations (4 passes) + extrapolation.
  dim3 pg(NS / 64, NBATCH);
  sink_pass_kernel<1><<<pg, 256, 0, stream>>>(Kmat, nullptr, swv, ua);   // u1
  sink_pass_kernel<0><<<pg, 256, 0, stream>>>(KTmat, ua, gwv, va);       // v1
  sink_pass_kernel<0><<<pg, 256, 0, stream>>>(Kmat, va, swv, ub);        // u2
  sink_pass_kernel<0><<<pg, 256, 0, stream>>>(KTmat, ub, gwv, vb);       // v2

  // G = sum_{j=1}^{100-M_REAL} fi^(2j) in double
  double fi2 = (10.0 / 10.1) * (10.0 / 10.1);
  double Gd = 0.0, pd = 1.0;
  for (int j = 0; j < (N_TOT - M_REAL); j++) { pd *= fi2; Gd += pd; }
  sink_final_kernel<<<32, 512, 0, stream>>>(ua, ub, va, vb, uv, vv, (float)Gd);

  // 7. gTv[h][g] = v[g]*g[g][h] (wide transpose + scale)
  wide_transpose_kernel<1><<<dim3(16, 16, 32), 256, 0, stream>>>(
      g_bf, gTv, vv, NG, NH);

  // 8. aligned = u .* (K @ gTv)  (per batch 512x1024, K=512)
  gemm_bt_kernel<2, 8, 4><<<1024, 256, 0, stream>>>(
      Kmat, gTv, 512, (size_t)512 * 512, (size_t)1024 * 512,
      out, (size_t)512 * 1024, 1024, nullptr, nullptr, nullptr, nullptr, uv);
}

// Round 16
// 186.098 us; speedup vs baseline: 1.0359x; 1.0144x over previous
//
#include <hip/hip_runtime.h>
#include <hip/hip_bf16.h>
#include <math.h>

// EmbeddingAlignerOT on MI355X.
// R16: GEMM1 was LDS-READ-bound (48 ds_read_b128/wave/tile x 8 waves x 16
// tiles x ~12cyc = 30.7us/CU > 16.5us MFMA floor). Register-block: read all
// 8 B-frags ONCE per tile (32 VGPR), then per (mq,mf) read 2 A-frags and
// fire 8 MFMAs. 24 reads/tile/wave = the minimum (24KB). Same k-order per
// accumulator -> bit-identical output. Rest: R15 verbatim.
// Workspace (~103.2 MB): [0,32M) s_bf -> K+KT after gemm1 | [32M,34M) W_bf ->
// ua/ub/va/vb | [34M,66M) g_bf | [66M,98M) t_bf -> gTv | [98M..) scalars.

typedef __bf16 bf16_t;
typedef __bf16 bf16x8 __attribute__((ext_vector_type(8)));
typedef float  f32x4  __attribute__((ext_vector_type(4)));

#define NBATCH 32
#define NS 512
#define NG 512
#define NH 1024
#define M_REAL 2
#define N_TOT 100

__device__ __forceinline__ void async_copy16(const void* gsrc, void* ldst) {
  __builtin_amdgcn_global_load_lds(
      (__attribute__((address_space(1))) void*)gsrc,
      (__attribute__((address_space(3))) void*)ldst, 16, 0, 0);
}

// ---------- fp32 -> bf16 convert, src and W in one dispatch ----------
__global__ __launch_bounds__(256) void cvt2_kernel(const float* __restrict__ a,
                                                   bf16_t* __restrict__ outa, int n8a,
                                                   const float* __restrict__ b,
                                                   bf16_t* __restrict__ outb) {
  int i = blockIdx.x * 256 + threadIdx.x;
  const float* src;
  bf16_t* dst;
  int idx;
  if (i < n8a) { src = a; dst = outa; idx = i; }
  else         { src = b; dst = outb; idx = i - n8a; }
  const float4* p = (const float4*)src + (size_t)idx * 2;
  float4 x = p[0], y = p[1];
  bf16x8 o;
  o[0] = (__bf16)x.x; o[1] = (__bf16)x.y; o[2] = (__bf16)x.z; o[3] = (__bf16)x.w;
  o[4] = (__bf16)y.x; o[5] = (__bf16)y.y; o[6] = (__bf16)y.z; o[7] = (__bf16)y.w;
  ((bf16x8*)dst)[idx] = o;
}

// ---------- target: convert to bf16 + fp32 row norms ----------
__global__ __launch_bounds__(128) void prep_g_kernel(const float* __restrict__ g,
                                                     bf16_t* __restrict__ gb,
                                                     float* __restrict__ g2) {
  int row = blockIdx.x;   // B*G rows of length NH
  int t = threadIdx.x;    // 128
  const float* rp = g + (size_t)row * NH + t * 8;
  float4 a = *(const float4*)rp;
  float4 b = *(const float4*)(rp + 4);
  bf16x8 o;
  o[0] = (__bf16)a.x; o[1] = (__bf16)a.y; o[2] = (__bf16)a.z; o[3] = (__bf16)a.w;
  o[4] = (__bf16)b.x; o[5] = (__bf16)b.y; o[6] = (__bf16)b.z; o[7] = (__bf16)b.w;
  ((bf16x8*)(gb + (size_t)row * NH))[t] = o;
  float ss = a.x*a.x + a.y*a.y + a.z*a.z + a.w*a.w
           + b.x*b.x + b.y*b.y + b.z*b.z + b.w*b.w;
  #pragma unroll
  for (int ofs = 32; ofs > 0; ofs >>= 1) ss += __shfl_down(ss, ofs);
  __shared__ float wsum[2];
  if ((t & 63) == 0) wsum[t >> 6] = ss;
  __syncthreads();
  if (t == 0) g2[row] = wsum[0] + wsum[1];
}

// ---------- adjusted weights for BOTH sides in one dispatch ----------
__global__ __launch_bounds__(512) void weights2_kernel(
    const float* __restrict__ s2, const int* __restrict__ smask, float* __restrict__ swv,
    const float* __restrict__ g2, const int* __restrict__ gmask, float* __restrict__ gwv) {
  int which = blockIdx.x >> 5;
  int bb = blockIdx.x & 31, t = threadIdx.x;
  const float* n2 = which ? g2 : s2;
  const int* mask = which ? gmask : smask;
  float* wout = which ? gwv : swv;
  int idx = bb * 512 + t;
  float mag = sqrtf(n2[idx]) + 1e-12f;
  float w = (float)mask[idx] * mag + 1e-12f;
  float ss = w;
  #pragma unroll
  for (int ofs = 32; ofs > 0; ofs >>= 1) ss += __shfl_down(ss, ofs);
  __shared__ float red[8];
  __shared__ float tot;
  if ((t & 63) == 0) red[t >> 6] = ss;
  __syncthreads();
  if (t == 0) {
    float x = 0.f;
    #pragma unroll
    for (int i = 0; i < 8; i++) x += red[i];
    tot = fmaxf(x, 1e-12f);
  }
  __syncthreads();
  wout[idx] = w / tot;
}

// ---------- GEMM1: t = A @ W^T + bias, 256x256 tile, 8-wave pipeline ----------
// M=16384, N=1024, K=1024. Grid 256 blocks (1/CU), 512 threads.
// LDS[buf][A/B][256*64] bf16, chunk-XOR swizzle LDS[r][ch]=g[r][ch^(r&7)].
// Per K-tile: stage_all(T+1) at top; read ALL 8 B-frags once; per (mq,mf)
// read 2 A-frags -> 8 MFMAs each; one vmcnt(0)+barrier per tile.
// 24 ds_read_b128/wave/tile (minimum) vs R15's 48.
// Fused row-norm: sum (val+bias)^2 -> atomicAdd s2out (s2out pre-zeroed).
__global__ __launch_bounds__(512) void gemm1_8ph_kernel(
    const bf16_t* __restrict__ A, const bf16_t* __restrict__ Bm,
    bf16_t* __restrict__ outp, const float* __restrict__ bias,
    float* __restrict__ s2out) {
  constexpr int K = 1024;
  __shared__ bf16_t lds[2][2][256 * 64];   // 128 KB
  const int nwg = gridDim.x;               // 256
  const int lin = blockIdx.x;
  const int lin2 = (lin & 7) * (nwg >> 3) + (lin >> 3);  // XCD swizzle
  const int bx = lin2 & 3;                 // 1024/256 = 4 col tiles
  const int by = lin2 >> 2;                // 64 row tiles
  const int tid = threadIdx.x, lane = tid & 63, w = tid >> 6;  // 8 waves
  const int wr = w >> 2, wc = w & 3;       // 2 x 4 wave grid
  const int m0 = by * 256, n0 = bx * 256;  // n0 in [0,1024)
  // staging lane coords: slab = 8 rows x 64 cols; lane covers row sRow, chunk lane&7
  const int sRow = lane >> 3;
  const int sc8 = ((lane & 7) ^ sRow) * 8;   // pre-swizzled global chunk
  // fragment read coords
  const int rF = lane & 15;
  const int cx = lane & 7;                   // == rowF & 7
  const int ch0 = (((lane >> 4)) ^ cx) * 8;  // ksub=0 swizzled chunk (elems)
  const int ch1 = ch0 ^ 32;                  // ksub=1

  // stage the ENTIRE A+B K-tile `tile` (8 loads: 4 A-slabs + 4 B-slabs)
  auto stage_all = [&](int tile) {
    const int buf = tile & 1;
    const int kt = tile << 6;
    #pragma unroll
    for (int j = 0; j < 4; j++) {
      int rA = wr * 128 + (4 * wc + j) * 8;
      async_copy16(A + (size_t)(m0 + rA + sRow) * K + kt + sc8,
                   &lds[buf][0][rA * 64]);
      int wB = wr * 2 + (wc & 1);
      int rB = (wc >> 1) * 128 + (4 * wB + j) * 8;
      async_copy16(Bm + (size_t)(n0 + rB + sRow) * K + kt + sc8,
                   &lds[buf][1][rB * 64]);
    }
  };

  f32x4 acc[8][4];
  #pragma unroll
  for (int i = 0; i < 8; i++)
    #pragma unroll
    for (int j = 0; j < 4; j++) { f32x4 z = {0.f, 0.f, 0.f, 0.f}; acc[i][j] = z; }

  stage_all(0);
  asm volatile("s_waitcnt vmcnt(0)" ::: "memory");
  __builtin_amdgcn_s_barrier();

  for (int T = 0; T < 16; ++T) {
    if (T < 15) stage_all(T + 1);     // into buf[(T+1)&1]; readers passed barrier
    const bf16_t* lA = &lds[T & 1][0][0];
    const bf16_t* lB = &lds[T & 1][1][0];
    // read ALL B fragments for this wave's 64 cols once (8 reads, 32 VGPR)
    bf16x8 bfr[4][2];
    #pragma unroll
    for (int nc = 0; nc < 4; nc++) {  // nc = nq*2+nf, 4 col-subtiles of 16
      int row = (wc * 64 + nc * 16 + rF) * 64;
      bfr[nc][0] = *(const bf16x8*)&lB[row + ch0];
      bfr[nc][1] = *(const bf16x8*)&lB[row + ch1];
    }
    #pragma unroll
    for (int mq = 0; mq < 2; mq++) {
      #pragma unroll
      for (int mf = 0; mf < 4; mf++) {
        int row = (wr * 128 + mq * 64 + mf * 16 + rF) * 64;
        bf16x8 af0 = *(const bf16x8*)&lA[row + ch0];
        bf16x8 af1 = *(const bf16x8*)&lA[row + ch1];
        __builtin_amdgcn_s_setprio(1);
        #pragma unroll
        for (int nc = 0; nc < 4; nc++) {
          acc[mq * 4 + mf][nc] = __builtin_amdgcn_mfma_f32_16x16x32_bf16(
              af0, bfr[nc][0], acc[mq * 4 + mf][nc], 0, 0, 0);
          acc[mq * 4 + mf][nc] = __builtin_amdgcn_mfma_f32_16x16x32_bf16(
              af1, bfr[nc][1], acc[mq * 4 + mf][nc], 0, 0, 0);
        }
        __builtin_amdgcn_s_setprio(0);
      }
    }
    if (T < 15)
      asm volatile("s_waitcnt vmcnt(0)" ::: "memory");  // T+1 loads: full-tile cover
    __builtin_amdgcn_s_barrier();     // buf[T&1] reads done; T+1 data visible
  }

  // epilogue: C/D mapping col=lane&15, row=(lane>>4)*4+j
  // acc[mq*4+mf][nc] covers rows wr*128+mq*64+mf*16, cols wc*64+nc*16
  const int r_off = (lane >> 4) * 4, c_off = lane & 15;
  float bs[4];
  #pragma unroll
  for (int ni = 0; ni < 4; ni++)
    bs[ni] = bias[n0 + wc * 64 + ni * 16 + c_off];
  float p[8][4];
  #pragma unroll
  for (int mi = 0; mi < 8; mi++)
    #pragma unroll
    for (int j = 0; j < 4; j++) p[mi][j] = 0.f;
  #pragma unroll
  for (int mi = 0; mi < 8; mi++) {
    int gm = m0 + wr * 128 + (mi >> 2) * 64 + (mi & 3) * 16 + r_off;
    #pragma unroll
    for (int ni = 0; ni < 4; ni++) {
      int gn = n0 + wc * 64 + ni * 16 + c_off;
      #pragma unroll
      for (int j = 0; j < 4; j++) {
        float tv = acc[mi][ni][j] + bs[ni];
        outp[(size_t)(gm + j) * 1024 + gn] = (__bf16)tv;
        p[mi][j] += tv * tv;
      }
    }
  }
  #pragma unroll
  for (int mi = 0; mi < 8; mi++) {
    int gm = m0 + wr * 128 + (mi >> 2) * 64 + (mi & 3) * 16 + r_off;
    #pragma unroll
    for (int j = 0; j < 4; j++) {
      float v = p[mi][j];
      v += __shfl_xor(v, 1);
      v += __shfl_xor(v, 2);
      v += __shfl_xor(v, 4);
      v += __shfl_xor(v, 8);
      if ((lane & 15) == 0) atomicAdd(&s2out[gm + j], v);
    }
  }
}

// ---------- C = A * B^T, 128x128 tile, BK=32, 4 waves (GEMM2/3) ----------
// Double-buffered K-loop, stage-at-top, counted vmcnt(4), raw barriers,
// chunk-XOR swizzle, XCD-aware bijective block swizzle.
// MODE 1: K = exp(-10*(sqrt(s2+g2-2C)*sw*gw+eps)) bf16 store (batched)
// MODE 2: out = u .* C, fp32 store (batched)
template <int MODE, int GX, int GY>
__global__ __launch_bounds__(256) void gemm_bt_kernel(
    const bf16_t* __restrict__ A, const bf16_t* __restrict__ Bm, int K_len,
    size_t strideAb, size_t strideBb,
    void* __restrict__ outp, size_t strideOb, int ldc,
    const float* __restrict__ s2, const float* __restrict__ g2,
    const float* __restrict__ sw, const float* __restrict__ gw,
    const float* __restrict__ uvec) {
  __shared__ bf16_t lds[2][2][128 * 32];   // [buf][A=0/B=1][row*32+col]
  const int nwg = gridDim.x;
  const int lin = blockIdx.x;
  const int lin2 = (lin & 7) * (nwg >> 3) + (lin >> 3);
  const int bx = lin2 % GX;
  const int by = (lin2 / GX) % GY;
  const int bz = lin2 / (GX * GY);
  const int tid = threadIdx.x, lane = tid & 63, wave = tid >> 6;
  const int wr = wave >> 1, wc = wave & 1;
  const bf16_t* Ab = A + (size_t)bz * strideAb;
  const bf16_t* Bb = Bm + (size_t)bz * strideBb;
  const int m0 = by * 128, n0 = bx * 128;
  const int rA = lane >> 2;
  const int c8s = (((lane & 3) ^ (rA & 3))) * 8;

  auto stage = [&](int kt, int buf) {
    #pragma unroll
    for (int c = 0; c < 2; c++) {
      int rg = (c * 4 + wave) * 16;
      async_copy16(Ab + (size_t)(m0 + rg + rA) * K_len + kt + c8s, &lds[buf][0][rg * 32]);
      async_copy16(Bb + (size_t)(n0 + rg + rA) * K_len + kt + c8s, &lds[buf][1][rg * 32]);
    }
  };

  f32x4 acc[4][4];
  #pragma unroll
  for (int i = 0; i < 4; i++)
    #pragma unroll
    for (int j = 0; j < 4; j++) { f32x4 z = {0.f, 0.f, 0.f, 0.f}; acc[i][j] = z; }

  const int chF = ((lane >> 4) ^ (lane & 3)) * 8;
  const int rF = lane & 15;

  stage(0, 0);
  int bufsel = 0;
  for (int kt = 0; kt < K_len; kt += 32) {
    if (kt + 32 < K_len) {
      stage(kt + 32, bufsel ^ 1);
      asm volatile("s_waitcnt vmcnt(4)" ::: "memory");
    } else {
      asm volatile("s_waitcnt vmcnt(0)" ::: "memory");
    }
    __builtin_amdgcn_s_barrier();
    bf16x8 af[4], bf[4];
    #pragma unroll
    for (int m = 0; m < 4; m++)
      af[m] = *(const bf16x8*)&lds[bufsel][0][(wr * 64 + m * 16 + rF) * 32 + chF];
    #pragma unroll
    for (int n = 0; n < 4; n++)
      bf[n] = *(const bf16x8*)&lds[bufsel][1][(wc * 64 + n * 16 + rF) * 32 + chF];
    #pragma unroll
    for (int m = 0; m < 4; m++)
      #pragma unroll
      for (int n = 0; n < 4; n++)
        acc[m][n] = __builtin_amdgcn_mfma_f32_16x16x32_bf16(af[m], bf[n], acc[m][n], 0, 0, 0);
    __builtin_amdgcn_s_barrier();
    bufsel ^= 1;
  }

  const int bo = bz * 512;
  const int row_base = m0 + wr * 64, col_base = n0 + wc * 64;
  const int r_off = (lane >> 4) * 4, c_off = lane & 15;
  #pragma unroll
  for (int m = 0; m < 4; m++) {
    #pragma unroll
    for (int n = 0; n < 4; n++) {
      #pragma unroll
      for (int j = 0; j < 4; j++) {
        int gm = row_base + m * 16 + r_off + j;
        int gn = col_base + n * 16 + c_off;
        float val = acc[m][n][j];
        if (MODE == 1) {
          float sq = s2[bo + gm] + g2[bo + gn] - 2.0f * val;
          float d = sqrtf(fmaxf(sq, 0.0f));
          float cost = d * sw[bo + gm] * gw[bo + gn] + 1e-12f;
          ((bf16_t*)outp + (size_t)bz * strideOb)[(size_t)gm * ldc + gn] =
              (__bf16)expf(-10.0f * cost);
        } else {
          ((float*)outp + (size_t)bz * strideOb)[(size_t)gm * ldc + gn] =
              uvec[bo + gm] * val;
        }
      }
    }
  }
}

// ---------- wide transpose: out[c][r] = in[r][c] * (SCALE ? v[r] : 1) ----------
template <int SCALE>
__global__ __launch_bounds__(256) void wide_transpose_kernel(
    const bf16_t* __restrict__ in, bf16_t* __restrict__ out,
    const float* __restrict__ vscale, int inRows, int inCols) {
  __shared__ bf16_t tl[32][66];
  size_t base = (size_t)blockIdx.z * inRows * inCols;
  int r0 = blockIdx.y * 32, c0 = blockIdx.x * 64;
  int row = threadIdx.x >> 3, cc8 = (threadIdx.x & 7) * 8;
  *(bf16x8*)&tl[row][cc8] =
      *(const bf16x8*)(in + base + (size_t)(r0 + row) * inCols + c0 + cc8);
  __syncthreads();
  int orow = threadIdx.x >> 2;
  int rq = (threadIdx.x & 3) * 8;
  bf16x8 o;
  if (SCALE) {
    const float* vp = vscale + (size_t)blockIdx.z * inRows + r0 + rq;
    float4 va = *(const float4*)vp;
    float4 vb = *(const float4*)(vp + 4);
    o[0] = (__bf16)((float)tl[rq + 0][orow] * va.x);
    o[1] = (__bf16)((float)tl[rq + 1][orow] * va.y);
    o[2] = (__bf16)((float)tl[rq + 2][orow] * va.z);
    o[3] = (__bf16)((float)tl[rq + 3][orow] * va.w);
    o[4] = (__bf16)((float)tl[rq + 4][orow] * vb.x);
    o[5] = (__bf16)((float)tl[rq + 5][orow] * vb.y);
    o[6] = (__bf16)((float)tl[rq + 6][orow] * vb.z);
    o[7] = (__bf16)((float)tl[rq + 7][orow] * vb.w);
  } else {
    #pragma unroll
    for (int i = 0; i < 8; i++) o[i] = tl[rq + i][orow];
  }
  *(bf16x8*)(out + base + (size_t)(c0 + orow) * inRows + r0 + rq) = o;
}

// ---------- Sinkhorn half-iteration, grid-wide ----------
template <int INIT>
__global__ __launch_bounds__(256) void sink_pass_kernel(
    const bf16_t* __restrict__ Mmat, const float* __restrict__ x,
    const float* __restrict__ w, float* __restrict__ y) {
  const int b = blockIdx.y;
  const int t = threadIdx.x;
  __shared__ float xs[512];
  if (!INIT) {
    ((float2*)xs)[t] = ((const float2*)(x + b * 512))[t];
    __syncthreads();
  }
  const int row = blockIdx.x * 64 + (t >> 2);
  const int seg = t & 3;
  const bf16_t* rp = Mmat + ((size_t)b * 512 + row) * 512;
  float sum = 0.f;
  #pragma unroll
  for (int j = 0; j < 16; j++) {
    bf16x8 kv = *(const bf16x8*)(rp + seg * 8 + j * 32);
    if (INIT) {
      sum += (float)kv[0] + (float)kv[1] + (float)kv[2] + (float)kv[3] +
             (float)kv[4] + (float)kv[5] + (float)kv[6] + (float)kv[7];
    } else {
      const float4* xp = (const float4*)&xs[seg * 8 + j * 32];
      float4 x0 = xp[0], x1 = xp[1];
      sum += (float)kv[0] * x0.x + (float)kv[1] * x0.y + (float)kv[2] * x0.z +
             (float)kv[3] * x0.w + (float)kv[4] * x1.x + (float)kv[5] * x1.y +
             (float)kv[6] * x1.z + (float)kv[7] * x1.w;
    }
  }
  if (INIT) sum *= (1.0f / 512.0f);
  sum += __shfl_xor(sum, 1);
  sum += __shfl_xor(sum, 2);
  if (seg == 0)
    y[b * 512 + row] = powf(w[b * 512 + row] / sum, 10.0f / 10.1f);
}

// ---------- Sinkhorn closed-form extrapolation to iteration 100 ----------
__global__ __launch_bounds__(512) void sink_final_kernel(
    const float* __restrict__ ua, const float* __restrict__ ub,
    const float* __restrict__ va, const float* __restrict__ vb,
    float* __restrict__ u_out, float* __restrict__ v_out, float Gf) {
  const int b = blockIdx.x, t = threadIdx.x, idx = b * 512 + t;
  const float ubv = ub[idx], vbv = vb[idx];
  float su = logf(ubv / ua[idx]);
  float sv = logf(vbv / va[idx]);
  #pragma unroll
  for (int ofs = 32; ofs > 0; ofs >>= 1) {
    su += __shfl_down(su, ofs);
    sv += __shfl_down(sv, ofs);
  }
  __shared__ float r0[8], r1[8];
  __shared__ float mu, mv;
  if ((t & 63) == 0) { r0[t >> 6] = su; r1[t >> 6] = sv; }
  __syncthreads();
  if (t == 0) {
    float a = 0.f, c = 0.f;
    #pragma unroll
    for (int i = 0; i < 8; i++) { a += r0[i]; c += r1[i]; }
    mu = a / 512.f; mv = c / 512.f;
  }
  __syncthreads();
  u_out[idx] = ubv * expf(Gf * mu);
  v_out[idx] = vbv * expf(Gf * mv);
}

extern "C" void kernel_launch(void* const* d_in, const int* in_sizes, int n_in,
                              void* d_out, int out_size, void* d_ws, size_t ws_size,
                              hipStream_t stream) {
  (void)in_sizes; (void)n_in; (void)out_size; (void)ws_size;
  const float* src = (const float*)d_in[0];   // [32,512,1024]
  const float* tgt = (const float*)d_in[1];   // [32,512,1024]
  const int* smask = (const int*)d_in[2];     // [32,512]
  const int* gmask = (const int*)d_in[3];     // [32,512]
  const float* W   = (const float*)d_in[4];   // [1024,1024]
  const float* bias = (const float*)d_in[5];  // [1024]
  float* out = (float*)d_out;                 // [32,512,1024]

  uint8_t* ws = (uint8_t*)d_ws;
  bf16_t* s_bf  = (bf16_t*)(ws + 0);          // 32 MB
  bf16_t* Kmat  = (bf16_t*)(ws + 0);          // reuse after gemm1: 16 MB
  bf16_t* KTmat = (bf16_t*)(ws + 16777216);   // 16 MB
  bf16_t* W_bf  = (bf16_t*)(ws + 33554432);   // 2 MB
  float* ua = (float*)(ws + 33554432);        // overwrite W_bf after gemm1
  float* ub = ua + 16384;
  float* va = ub + 16384;
  float* vb = va + 16384;
  bf16_t* g_bf  = (bf16_t*)(ws + 35651584);   // 32 MB
  bf16_t* t_bf  = (bf16_t*)(ws + 69206016);   // 32 MB
  bf16_t* gTv   = (bf16_t*)(ws + 69206016);   // reuse after gemm2
  float* s2  = (float*)(ws + 102760448);
  float* g2  = s2 + 16384;
  float* swv = g2 + 16384;
  float* gwv = swv + 16384;
  float* uv  = gwv + 16384;
  float* vv  = uv + 16384;

  // 1. conversions + g norms; zero s2 for fused-norm atomics
  cvt2_kernel<<<8704, 256, 0, stream>>>(src, s_bf, 2097152, W, W_bf);
  prep_g_kernel<<<16384, 128, 0, stream>>>(tgt, g_bf, g2);
  hipMemsetAsync(s2, 0, 16384 * sizeof(float), stream);

  // 2. t = s @ W^T + b  (M=16384,N=1024,K=1024) + fused row norms -> s2
  gemm1_8ph_kernel<<<256, 512, 0, stream>>>(s_bf, W_bf, t_bf, bias, s2);

  // 3. weights (both sides, one dispatch)
  weights2_kernel<<<64, 512, 0, stream>>>(s2, smask, swv, g2, gmask, gwv);

  // 4. K = exp(-10*cost)  (per batch 512x512, K=1024)
  gemm_bt_kernel<1, 4, 4><<<512, 256, 0, stream>>>(
      t_bf, g_bf, 1024, (size_t)512 * 1024, (size_t)512 * 1024,
      Kmat, (size_t)512 * 512, 512, s2, g2, swv, gwv, nullptr);

  // 5. K^T (wide transpose)
  wide_transpose_kernel<0><<<dim3(8, 16, 32), 256, 0, stream>>>(
      Kmat, KTmat, nullptr, NS, NG);

  // 6. Sinkhorn: 2 real iterations (4 passes) + extrapolation.
  dim3 pg(NS / 64, NBATCH);
  sink_pass_kernel<1><<<pg, 256, 0, stream>>>(Kmat, nullptr, swv, ua);   // u1
  sink_pass_kernel<0><<<pg, 256, 0, stream>>>(KTmat, ua, gwv, va);       // v1
  sink_pass_kernel<0><<<pg, 256, 0, stream>>>(Kmat, va, swv, ub);        // u2
  sink_pass_kernel<0><<<pg, 256, 0, stream>>>(KTmat, ub, gwv, vb);       // v2

  // G = sum_{j=1}^{100-M_REAL} fi^(2j) in double
  double fi2 = (10.0 / 10.1) * (10.0 / 10.1);
  double Gd = 0.0, pd = 1.0;
  for (int j = 0; j < (N_TOT - M_REAL); j++) { pd *= fi2; Gd += pd; }
  sink_final_kernel<<<32, 512, 0, stream>>>(ua, ub, va, vb, uv, vv, (float)Gd);

  // 7. gTv[h][g] = v[g]*g[g][h] (wide transpose + scale)
  wide_transpose_kernel<1><<<dim3(16, 16, 32), 256, 0, stream>>>(
      g_bf, gTv, vv, NG, NH);

  // 8. aligned = u .* (K @ gTv)  (per batch 512x1024, K=512)
  gemm_bt_kernel<2, 8, 4><<<1024, 256, 0, stream>>>(
      Kmat, gTv, 512, (size_t)512 * 512, (size_t)1024 * 512,
      out, (size_t)512 * 1024, 1024, nullptr, nullptr, nullptr, nullptr, uv);
}